// Round 3
// baseline (331.379 us; speedup 1.0000x reference)
//
#include <hip/hip_runtime.h>
#include <hip/hip_bf16.h>

// B=4, S=1024, D=1024, H=16, DH=64. Softmax over HEADS (per (i,j)), per reference.

using f32x4  = __attribute__((ext_vector_type(4))) float;
using bf16x8 = __attribute__((ext_vector_type(8))) short;

__device__ inline unsigned short f2b(float f){
    unsigned u = __float_as_uint(f);
    unsigned r = (u + 0x7fffu + ((u >> 16) & 1u)) >> 16;
    return (unsigned short)r;
}
__device__ inline float b2f(unsigned short s){
    return __uint_as_float(((unsigned)s) << 16);
}

#define GLL16(gp, lp) __builtin_amdgcn_global_load_lds( \
    (const __attribute__((address_space(1))) void*)(gp), \
    (__attribute__((address_space(3))) void*)(lp), 16, 0, 0)

// ---------------- convert q,k,v f32 -> bf16, contiguous [3][4096][1024] -------
__global__ __launch_bounds__(256) void convert_qkv(
    const float* __restrict__ q, const float* __restrict__ k, const float* __restrict__ v,
    unsigned short* __restrict__ dst)
{
    const long gid = (long)blockIdx.x * 256 + threadIdx.x;   // group of 4 floats
    const int  t   = (int)(gid >> 20);                       // 1048576 groups per tensor
    const long off = (gid & 1048575) << 2;
    const float* src = (t == 0) ? q : (t == 1) ? k : v;
    const float4 x = *(const float4*)(src + off);
    ushort4 o;
    o.x = f2b(x.x); o.y = f2b(x.y); o.z = f2b(x.z); o.w = f2b(x.w);
    *(ushort4*)(dst + (long)t * 4194304 + off) = o;
}

// ---------------- transpose+convert W f32 [k][n] -> bf16 [n][k] ---------------
__global__ __launch_bounds__(256) void wtrans(
    const float* __restrict__ w0, const float* __restrict__ w1,
    const float* __restrict__ w2, const float* __restrict__ w3,
    unsigned short* __restrict__ out)
{
    const float* W = (blockIdx.z == 0) ? w0 : (blockIdx.z == 1) ? w1 : (blockIdx.z == 2) ? w2 : w3;
    unsigned short* O = out + (long)blockIdx.z * 1048576;
    __shared__ float t[32][33];
    const int n0 = blockIdx.x * 32, k0 = blockIdx.y * 32;
    const int tx = threadIdx.x, ty = threadIdx.y;   // (32,8)
    #pragma unroll
    for (int i = 0; i < 4; i++)
        t[ty + 8*i][tx] = W[(long)(k0 + ty + 8*i) * 1024 + n0 + tx];
    __syncthreads();
    #pragma unroll
    for (int i = 0; i < 4; i++)
        O[(long)(n0 + ty + 8*i) * 1024 + k0 + tx] = f2b(t[tx][ty + 8*i]);
}

// ---------------- transpose V bf16 [b*1024+s][d] -> Vt [b][d][s] --------------
__global__ __launch_bounds__(256) void vtrans(
    const unsigned short* __restrict__ V, unsigned short* __restrict__ Vt)
{
    const int b = blockIdx.z;
    __shared__ unsigned short t[32][33];
    const int s0 = blockIdx.x * 32, d0 = blockIdx.y * 32;
    const int tx = threadIdx.x, ty = threadIdx.y;
    #pragma unroll
    for (int i = 0; i < 4; i++)
        t[ty + 8*i][tx] = V[(long)(b*1024 + s0 + ty + 8*i) * 1024 + d0 + tx];
    __syncthreads();
    #pragma unroll
    for (int i = 0; i < 4; i++)
        Vt[(long)b * 1048576 + (long)(d0 + ty + 8*i) * 1024 + s0 + tx] = t[tx][ty + 8*i];
}

// ---------------- GEMM tile body (m97 structure) ------------------------------
template<int OUTF32>
__device__ __forceinline__ void gemm_body(
    const unsigned short* __restrict__ A,
    const unsigned short* __restrict__ BT,
    const float* __restrict__ bias,
    void* __restrict__ Cout, int N, int K,
    unsigned short* As, unsigned short* Bs)
{
    const int tid  = threadIdx.x;
    const int wave = tid >> 6, lane = tid & 63;
    const int l15  = lane & 15, l4 = lane >> 4;
    const int wr   = wave >> 1, wc = wave & 1;
    const long rowBase = (long)blockIdx.x * 128;
    const long colBase = (long)blockIdx.y * 128;

    f32x4 acc[4][4];
    #pragma unroll
    for (int m = 0; m < 4; m++)
        #pragma unroll
        for (int n = 0; n < 4; n++)
            acc[m][n] = (f32x4){0.f, 0.f, 0.f, 0.f};

    const int c0    = wave * 2;
    const int srow0 = c0 * 16 + (lane >> 2);
    const int srow1 = srow0 + 16;
    const int skk   = (lane & 3) * 8;

    for (int k0 = 0; k0 < K; k0 += 32) {
        GLL16(A  + (rowBase + srow0) * K + k0 + skk, As + c0 * 512);
        GLL16(A  + (rowBase + srow1) * K + k0 + skk, As + (c0 + 1) * 512);
        GLL16(BT + (colBase + srow0) * K + k0 + skk, Bs + c0 * 512);
        GLL16(BT + (colBase + srow1) * K + k0 + skk, Bs + (c0 + 1) * 512);
        __syncthreads();
        bf16x8 af[4], bfr[4];
        #pragma unroll
        for (int m = 0; m < 4; m++)
            af[m] = *(const bf16x8*)(As + (wr*64 + m*16 + l15) * 32 + l4 * 8);
        #pragma unroll
        for (int n = 0; n < 4; n++)
            bfr[n] = *(const bf16x8*)(Bs + (wc*64 + n*16 + l15) * 32 + l4 * 8);
        #pragma unroll
        for (int m = 0; m < 4; m++)
            #pragma unroll
            for (int n = 0; n < 4; n++)
                acc[m][n] = __builtin_amdgcn_mfma_f32_16x16x32_bf16(af[m], bfr[n], acc[m][n], 0, 0, 0);
        __syncthreads();
    }

    #pragma unroll
    for (int m = 0; m < 4; m++) {
        const long row = rowBase + wr*64 + m*16 + l4*4;
        #pragma unroll
        for (int n = 0; n < 4; n++) {
            const long col = colBase + wc*64 + n*16 + l15;
            const float bv = bias[col];
            #pragma unroll
            for (int r = 0; r < 4; r++) {
                const float vv = acc[m][n][r] + bv;
                if (OUTF32) ((float*)Cout)[(row + r) * N + col] = vv;
                else        ((unsigned short*)Cout)[(row + r) * N + col] = f2b(vv);
            }
        }
    }
}

// final output GEMM (f32 out)
__global__ __launch_bounds__(256) void gemm_bias_f32(
    const unsigned short* __restrict__ A,
    const unsigned short* __restrict__ BT,
    const float* __restrict__ bias,
    float* __restrict__ Cout, int N, int K)
{
    __shared__ unsigned short As[128 * 32];
    __shared__ unsigned short Bs[128 * 32];
    gemm_body<1>(A, BT, bias, (void*)Cout, N, K, As, Bs);
}

// batched Q/K/V projection GEMMs: blockIdx.z selects tensor (3x occupancy)
__global__ __launch_bounds__(256) void gemm3(
    const unsigned short* __restrict__ Abase,   // Xq | Xk | Xv  (stride 4M elems)
    const unsigned short* __restrict__ WT,      // 3 weights (stride 1M elems)
    const float* __restrict__ bq, const float* __restrict__ bk, const float* __restrict__ bv,
    unsigned short* __restrict__ Cbase)         // Qm | Km | Vm  (stride 4M elems)
{
    __shared__ unsigned short As[128 * 32];
    __shared__ unsigned short Bs[128 * 32];
    const int z = blockIdx.z;
    const unsigned short* A  = Abase + (long)z * 4194304;
    const unsigned short* BT = WT    + (long)z * 1048576;
    unsigned short*       C  = Cbase + (long)z * 4194304;
    const float* bias = (z == 0) ? bq : (z == 1) ? bk : bv;
    gemm_body<0>(A, BT, bias, (void*)C, 1024, 1024, As, Bs);
}

// ---------------- fused attention ---------------------------------------------
// Block: (b, 16 i-rows, j-half of 512). K/V tiles (32 j x 1024 d = 64KB) staged
// via global_load_lds into ONE shared LDS buffer in chunk-column layout
// [16B-chunk][row]  -> conflict-free ds_read_b128 fragment reads.
// Timeline/iter: QK(K in LDS) | stage V + head-softmax | PV(V in LDS) | stage K(t+1)
__global__ __launch_bounds__(512) void attn_fused(
    const unsigned short* __restrict__ Q,    // [4096][1024]
    const unsigned short* __restrict__ Kg_,  // [4096][1024]
    const unsigned short* __restrict__ Vt,   // [4][1024(d)][1024(s)]
    const int* __restrict__ mask,            // [1024*1024]
    unsigned short* __restrict__ P0,         // partial jh=0
    unsigned short* __restrict__ P1)         // partial jh=1
{
    __shared__ unsigned short KV[32768];           // 64KB, K/V time-shared
    __shared__ float s_lds[16 * 32 * 17];          // scores [(i*32+j)*17 + h]
    __shared__ unsigned short p_lds[16 * 16 * 40]; // P [h*640 + i*40 + j]

    const int tid  = threadIdx.x;
    const int wave = tid >> 6, lane = tid & 63;
    const int l15  = lane & 15, l4 = lane >> 4;

    // bijective XCD swizzle (nwg=512, 64 blocks/XCD -> one batch's K/V per L2)
    const int lin = blockIdx.x + 64 * (blockIdx.y + 2 * blockIdx.z);
    const int wg  = (lin & 7) * 64 + (lin >> 3);
    const int b   = wg >> 7;
    const int jh  = (wg >> 6) & 1;
    const int i0  = (wg & 63) << 4;
    const int jbase = jh << 9;

    const unsigned short* Kb = Kg_ + (long)b * 1048576;
    const unsigned short* Vb = Vt  + (long)b * 1048576;
    unsigned short* Pout = (jh == 0) ? P0 : P1;

    // ---- stage K(t=0): lds linear; per-lane global src realizes chunk-column layout
    #pragma unroll
    for (int u = 0; u < 8; u++) {
        const int L = u * 8192 + tid * 16;          // byte offset in tile
        const int row = (L >> 4) & 31, cc = L >> 9; // K: [cc 0..127][row 0..31]
        GLL16(Kb + (long)(jbase + row) * 1024 + cc * 8, KV + u * 4096 + wave * 512);
    }

    // ---- Q fragments (one-time scattered global read)
    bf16x8 qf[2][2];
    {
        const unsigned short* Qrow = Q + (long)(b * 1024 + i0 + l15) * 1024;
        #pragma unroll
        for (int hh = 0; hh < 2; hh++) {
            const int h = wave * 2 + hh;
            qf[hh][0] = *(const bf16x8*)(Qrow + h * 64 + l4 * 8);
            qf[hh][1] = *(const bf16x8*)(Qrow + h * 64 + 32 + l4 * 8);
        }
    }
    f32x4 acc[2][4];
    #pragma unroll
    for (int a = 0; a < 2; a++)
        #pragma unroll
        for (int n = 0; n < 4; n++)
            acc[a][n] = (f32x4){0.f, 0.f, 0.f, 0.f};

    __syncthreads();   // S0: K(0) resident

    for (int t = 0; t < 16; t++) {
        const int j0 = jbase + t * 32;
        // prefetch mask for this tile (consumed in softmax, hidden under QK)
        const int mk = mask[(i0 + (tid >> 5)) * 1024 + j0 + (tid & 31)];

        // ---- QK^T from LDS K-tile: chunk cc = h*8 + half*4 + l4
        #pragma unroll
        for (int hh = 0; hh < 2; hh++) {
            const int h = wave * 2 + hh;
            #pragma unroll
            for (int n = 0; n < 2; n++) {
                bf16x8 kf0 = *(const bf16x8*)(KV + (h * 8 + l4) * 256 + (n * 16 + l15) * 8);
                bf16x8 kf1 = *(const bf16x8*)(KV + (h * 8 + 4 + l4) * 256 + (n * 16 + l15) * 8);
                f32x4 s = (f32x4){0.f, 0.f, 0.f, 0.f};
                s = __builtin_amdgcn_mfma_f32_16x16x32_bf16(qf[hh][0], kf0, s, 0, 0, 0);
                s = __builtin_amdgcn_mfma_f32_16x16x32_bf16(qf[hh][1], kf1, s, 0, 0, 0);
                #pragma unroll
                for (int r = 0; r < 4; r++)
                    s_lds[((l4 * 4 + r) * 32 + n * 16 + l15) * 17 + h] = s[r];
            }
        }
        __syncthreads();   // S1: K reads done, scores visible

        // ---- stage V(t) into the same buffer: V: [jc 0..3][dv 0..1023]
        #pragma unroll
        for (int u = 0; u < 8; u++) {
            const int L = u * 8192 + tid * 16;
            const int dv = (L >> 4) & 1023, jc = L >> 14;
            GLL16(Vb + (long)dv * 1024 + j0 + jc * 8, KV + u * 4096 + wave * 512);
        }

        // ---- head-softmax: one thread per (i,j); V staging latency hides here
        {
            const float* sp = s_lds + tid * 17;
            float sc[16];
            float mx = -1e30f;
            #pragma unroll
            for (int h = 0; h < 16; h++) {
                float vv = sp[h] * 0.125f;
                if (mk == 0) vv = -__builtin_inff();
                sc[h] = vv;
                mx = fmaxf(mx, vv);
            }
            float Z = 0.f;
            #pragma unroll
            for (int h = 0; h < 16; h++) {
                const float e = __expf(sc[h] - mx);
                sc[h] = e; Z += e;
            }
            const float inv = 1.f / Z;
            const int si = tid >> 5, sj = tid & 31;
            #pragma unroll
            for (int h = 0; h < 16; h++)
                p_lds[h * 640 + si * 40 + sj] = f2b(sc[h] * inv);
        }
        __syncthreads();   // S2: V resident, P visible

        // ---- PV from LDS V-tile: chunk (dv, jc=l4)
        #pragma unroll
        for (int hh = 0; hh < 2; hh++) {
            const int h = wave * 2 + hh;
            bf16x8 pf = *(const bf16x8*)(p_lds + h * 640 + l15 * 40 + l4 * 8);
            #pragma unroll
            for (int n = 0; n < 4; n++) {
                bf16x8 vf = *(const bf16x8*)(KV + l4 * 8192 + (h * 64 + n * 16 + l15) * 8);
                acc[hh][n] = __builtin_amdgcn_mfma_f32_16x16x32_bf16(pf, vf, acc[hh][n], 0, 0, 0);
            }
        }
        __syncthreads();   // S3: V reads done

        // ---- stage K(t+1)
        if (t < 15) {
            const int jn = j0 + 32;
            #pragma unroll
            for (int u = 0; u < 8; u++) {
                const int L = u * 8192 + tid * 16;
                const int row = (L >> 4) & 31, cc = L >> 9;
                GLL16(Kb + (long)(jn + row) * 1024 + cc * 8, KV + u * 4096 + wave * 512);
            }
        }
        __syncthreads();   // S4: K(t+1) resident
    }

    // ---- epilogue: bf16 partial
    #pragma unroll
    for (int hh = 0; hh < 2; hh++) {
        const int h = wave * 2 + hh;
        #pragma unroll
        for (int n = 0; n < 4; n++)
            #pragma unroll
            for (int r = 0; r < 4; r++) {
                const long row = b * 1024 + i0 + l4 * 4 + r;
                Pout[row * 1024 + h * 64 + n * 16 + l15] = f2b(acc[hh][n][r]);
            }
    }
}

// ---------------- reduce: P0 += P1 (bf16, in place) ---------------------------
__global__ __launch_bounds__(256) void addp(
    unsigned short* __restrict__ P0, const unsigned short* __restrict__ P1)
{
    const long i = ((long)blockIdx.x * 256 + threadIdx.x) * 8;
    ushort4 a0 = *(const ushort4*)(P0 + i);
    ushort4 a1 = *(const ushort4*)(P0 + i + 4);
    ushort4 b0 = *(const ushort4*)(P1 + i);
    ushort4 b1 = *(const ushort4*)(P1 + i + 4);
    ushort4 o0, o1;
    o0.x = f2b(b2f(a0.x) + b2f(b0.x)); o0.y = f2b(b2f(a0.y) + b2f(b0.y));
    o0.z = f2b(b2f(a0.z) + b2f(b0.z)); o0.w = f2b(b2f(a0.w) + b2f(b0.w));
    o1.x = f2b(b2f(a1.x) + b2f(b1.x)); o1.y = f2b(b2f(a1.y) + b2f(b1.y));
    o1.z = f2b(b2f(a1.z) + b2f(b1.z)); o1.w = f2b(b2f(a1.w) + b2f(b1.w));
    *(ushort4*)(P0 + i) = o0;
    *(ushort4*)(P0 + i + 4) = o1;
}

extern "C" void kernel_launch(void* const* d_in, const int* in_sizes, int n_in,
                              void* d_out, int out_size, void* d_ws, size_t ws_size,
                              hipStream_t stream)
{
    const float* q    = (const float*)d_in[0];
    const float* k    = (const float*)d_in[1];
    const float* v    = (const float*)d_in[2];
    const int*   mask = (const int*)  d_in[3];
    const float* Wq   = (const float*)d_in[4];
    const float* bq   = (const float*)d_in[5];
    const float* Wk   = (const float*)d_in[6];
    const float* bk   = (const float*)d_in[7];
    const float* Wv   = (const float*)d_in[8];
    const float* bv   = (const float*)d_in[9];
    const float* Wo   = (const float*)d_in[10];
    const float* bo   = (const float*)d_in[11];

    unsigned short* ws = (unsigned short*)d_ws;
    const long MS = 1048576;              // 1M bf16 elements = 2MB
    unsigned short* WT  = ws;             // 4 transposed weights      [0,4M)
    unsigned short* Xq  = ws + 4*MS;      // bf16 query  -> later Vt   [4M,8M)
    unsigned short* Xk  = ws + 8*MS;      // bf16 key    -> later P0   [8M,12M)
    unsigned short* Xv  = ws + 12*MS;     // bf16 value                [12M,16M)
    unsigned short* Qm  = ws + 16*MS;     // Q projection              [16M,20M)
    unsigned short* Km  = ws + 20*MS;     // K projection              [20M,24M)
    unsigned short* Vm  = ws + 24*MS;     // V projection -> later P1  [24M,28M)
    unsigned short* Vtm = Xq;             // V transposed (Xq dead after gemm3)
    unsigned short* P0  = Xk;             // attn partial jh=0 (Xk dead after gemm3)
    unsigned short* P1  = Vm;             // attn partial jh=1 (Vm dead after vtrans)

    convert_qkv<<<12288, 256, 0, stream>>>(q, k, v, Xq);
    wtrans<<<dim3(32, 32, 4), dim3(32, 8), 0, stream>>>(Wq, Wk, Wv, Wo, WT);
    gemm3<<<dim3(32, 8, 3), 256, 0, stream>>>(Xq, WT, bq, bk, bv, Qm);
    vtrans<<<dim3(32, 32, 4), dim3(32, 8), 0, stream>>>(Vm, Vtm);
    attn_fused<<<dim3(64, 2, 4), 512, 0, stream>>>(Qm, Km, Vtm, mask, P0, P1);
    addp<<<2048, 256, 0, stream>>>(P0, P1);
    gemm_bias_f32<<<dim3(32, 8), 256, 0, stream>>>(P0, WT + 3*MS, bo, (float*)d_out, 1024, 1024);
}

// Round 4
// 193.362 us; speedup vs baseline: 1.7138x; 1.7138x over previous
//
#include <hip/hip_runtime.h>
#include <hip/hip_bf16.h>

// B=4, S=1024, D=1024, H=16, DH=64. Softmax over HEADS (per (i,j)), per reference.

using f32x4  = __attribute__((ext_vector_type(4))) float;
using bf16x8 = __attribute__((ext_vector_type(8))) short;

__device__ inline unsigned short f2b(float f){
    unsigned u = __float_as_uint(f);
    unsigned r = (u + 0x7fffu + ((u >> 16) & 1u)) >> 16;
    return (unsigned short)r;
}
__device__ inline float b2f(unsigned short s){
    return __uint_as_float(((unsigned)s) << 16);
}

#define GLL16(gp, lp) __builtin_amdgcn_global_load_lds( \
    (const __attribute__((address_space(1))) void*)(gp), \
    (__attribute__((address_space(3))) void*)(lp), 16, 0, 0)

#define LGKM0 do { asm volatile("s_waitcnt lgkmcnt(0)" ::: "memory"); \
                   __builtin_amdgcn_sched_barrier(0); } while(0)
#define VM4   do { asm volatile("s_waitcnt vmcnt(4)" ::: "memory"); \
                   __builtin_amdgcn_sched_barrier(0); } while(0)
#define VM0   do { asm volatile("s_waitcnt vmcnt(0)" ::: "memory"); \
                   __builtin_amdgcn_sched_barrier(0); } while(0)
#define BAR   do { __builtin_amdgcn_s_barrier(); \
                   __builtin_amdgcn_sched_barrier(0); } while(0)

// ---------------- convert q,k,v f32 -> bf16, contiguous [3][4096][1024] -------
__global__ __launch_bounds__(256) void convert_qkv(
    const float* __restrict__ q, const float* __restrict__ k, const float* __restrict__ v,
    unsigned short* __restrict__ dst)
{
    const long gid = (long)blockIdx.x * 256 + threadIdx.x;
    const int  t   = (int)(gid >> 20);
    const long off = (gid & 1048575) << 2;
    const float* src = (t == 0) ? q : (t == 1) ? k : v;
    const float4 x = *(const float4*)(src + off);
    ushort4 o;
    o.x = f2b(x.x); o.y = f2b(x.y); o.z = f2b(x.z); o.w = f2b(x.w);
    *(ushort4*)(dst + (long)t * 4194304 + off) = o;
}

// ---------------- transpose+convert W f32 [k][n] -> bf16 [n][k] ---------------
__global__ __launch_bounds__(256) void wtrans(
    const float* __restrict__ w0, const float* __restrict__ w1,
    const float* __restrict__ w2, const float* __restrict__ w3,
    unsigned short* __restrict__ out)
{
    const float* W = (blockIdx.z == 0) ? w0 : (blockIdx.z == 1) ? w1 : (blockIdx.z == 2) ? w2 : w3;
    unsigned short* O = out + (long)blockIdx.z * 1048576;
    __shared__ float t[32][33];
    const int n0 = blockIdx.x * 32, k0 = blockIdx.y * 32;
    const int tx = threadIdx.x, ty = threadIdx.y;
    #pragma unroll
    for (int i = 0; i < 4; i++)
        t[ty + 8*i][tx] = W[(long)(k0 + ty + 8*i) * 1024 + n0 + tx];
    __syncthreads();
    #pragma unroll
    for (int i = 0; i < 4; i++)
        O[(long)(n0 + ty + 8*i) * 1024 + k0 + tx] = f2b(t[tx][ty + 8*i]);
}

// ---------------- transpose V bf16 [b*1024+s][d] -> Vt [b][d][s] --------------
__global__ __launch_bounds__(256) void vtrans(
    const unsigned short* __restrict__ V, unsigned short* __restrict__ Vt)
{
    const int b = blockIdx.z;
    __shared__ unsigned short t[32][33];
    const int s0 = blockIdx.x * 32, d0 = blockIdx.y * 32;
    const int tx = threadIdx.x, ty = threadIdx.y;
    #pragma unroll
    for (int i = 0; i < 4; i++)
        t[ty + 8*i][tx] = V[(long)(b*1024 + s0 + ty + 8*i) * 1024 + d0 + tx];
    __syncthreads();
    #pragma unroll
    for (int i = 0; i < 4; i++)
        Vt[(long)b * 1048576 + (long)(d0 + ty + 8*i) * 1024 + s0 + tx] = t[tx][ty + 8*i];
}

// ---------------- GEMM tile body (m97 structure) ------------------------------
template<int OUTF32>
__device__ __forceinline__ void gemm_body(
    const unsigned short* __restrict__ A,
    const unsigned short* __restrict__ BT,
    const float* __restrict__ bias,
    void* __restrict__ Cout, int N, int K,
    unsigned short* As, unsigned short* Bs)
{
    const int tid  = threadIdx.x;
    const int wave = tid >> 6, lane = tid & 63;
    const int l15  = lane & 15, l4 = lane >> 4;
    const int wr   = wave >> 1, wc = wave & 1;
    const long rowBase = (long)blockIdx.x * 128;
    const long colBase = (long)blockIdx.y * 128;

    f32x4 acc[4][4];
    #pragma unroll
    for (int m = 0; m < 4; m++)
        #pragma unroll
        for (int n = 0; n < 4; n++)
            acc[m][n] = (f32x4){0.f, 0.f, 0.f, 0.f};

    const int c0    = wave * 2;
    const int srow0 = c0 * 16 + (lane >> 2);
    const int srow1 = srow0 + 16;
    const int skk   = (lane & 3) * 8;

    for (int k0 = 0; k0 < K; k0 += 32) {
        GLL16(A  + (rowBase + srow0) * K + k0 + skk, As + c0 * 512);
        GLL16(A  + (rowBase + srow1) * K + k0 + skk, As + (c0 + 1) * 512);
        GLL16(BT + (colBase + srow0) * K + k0 + skk, Bs + c0 * 512);
        GLL16(BT + (colBase + srow1) * K + k0 + skk, Bs + (c0 + 1) * 512);
        __syncthreads();
        bf16x8 af[4], bfr[4];
        #pragma unroll
        for (int m = 0; m < 4; m++)
            af[m] = *(const bf16x8*)(As + (wr*64 + m*16 + l15) * 32 + l4 * 8);
        #pragma unroll
        for (int n = 0; n < 4; n++)
            bfr[n] = *(const bf16x8*)(Bs + (wc*64 + n*16 + l15) * 32 + l4 * 8);
        #pragma unroll
        for (int m = 0; m < 4; m++)
            #pragma unroll
            for (int n = 0; n < 4; n++)
                acc[m][n] = __builtin_amdgcn_mfma_f32_16x16x32_bf16(af[m], bfr[n], acc[m][n], 0, 0, 0);
        __syncthreads();
    }

    #pragma unroll
    for (int m = 0; m < 4; m++) {
        const long row = rowBase + wr*64 + m*16 + l4*4;
        #pragma unroll
        for (int n = 0; n < 4; n++) {
            const long col = colBase + wc*64 + n*16 + l15;
            const float bv = bias[col];
            #pragma unroll
            for (int r = 0; r < 4; r++) {
                const float vv = acc[m][n][r] + bv;
                if (OUTF32) ((float*)Cout)[(row + r) * N + col] = vv;
                else        ((unsigned short*)Cout)[(row + r) * N + col] = f2b(vv);
            }
        }
    }
}

__global__ __launch_bounds__(256) void gemm_bias_f32(
    const unsigned short* __restrict__ A,
    const unsigned short* __restrict__ BT,
    const float* __restrict__ bias,
    float* __restrict__ Cout, int N, int K)
{
    __shared__ unsigned short As[128 * 32];
    __shared__ unsigned short Bs[128 * 32];
    gemm_body<1>(A, BT, bias, (void*)Cout, N, K, As, Bs);
}

__global__ __launch_bounds__(256) void gemm3(
    const unsigned short* __restrict__ Abase,
    const unsigned short* __restrict__ WT,
    const float* __restrict__ bq, const float* __restrict__ bk, const float* __restrict__ bv,
    unsigned short* __restrict__ Cbase)
{
    __shared__ unsigned short As[128 * 32];
    __shared__ unsigned short Bs[128 * 32];
    const int z = blockIdx.z;
    const unsigned short* A  = Abase + (long)z * 4194304;
    const unsigned short* BT = WT    + (long)z * 1048576;
    unsigned short*       C  = Cbase + (long)z * 4194304;
    const float* bias = (z == 0) ? bq : (z == 1) ? bk : bv;
    gemm_body<0>(A, BT, bias, (void*)C, 1024, 1024, As, Bs);
}

// ---------------- fused attention ---------------------------------------------
// IBLK=32 i-rows, KVBLK=16 j-cols per iter, 32 iters over a 512-j half.
// K tile [j16][d1024] (XOR-swizzled source, coalesced), V tile [d1024][j16].
// Counted-vmcnt pipeline: K(t+1) issued after QK, V(t+1) after PV; vmcnt(4)
// waits, never vmcnt(0) in the steady loop.
__global__ __launch_bounds__(512) void attn_fused(
    const unsigned short* __restrict__ Q,    // [4096][1024]
    const unsigned short* __restrict__ Kg_,  // [4096][1024]
    const unsigned short* __restrict__ Vt,   // [4][1024(d)][1024(s)]
    const int* __restrict__ mask,            // [1024*1024]
    unsigned short* __restrict__ P0,
    unsigned short* __restrict__ P1)
{
    __shared__ __align__(16) unsigned char smem[141312];
    unsigned char* Ak = smem;                                   // 32768: K tile
    unsigned char* Bv = smem + 32768;                           // 32768: V tile
    float*          S = (float*)(smem + 65536);                 // 34816: [i32][j16][17]
    unsigned char* Pb = smem + 100352;                          // 40960: [h16][i32][j40] bf16

    const int tid = threadIdx.x, w = tid >> 6, lane = tid & 63;
    const int l15 = lane & 15, l4 = lane >> 4;
    const int h0 = 2 * w;

    // bijective XCD swizzle: 256 blocks -> 32 consecutive wg per XCD
    const int bid = blockIdx.x;
    const int wg  = (bid & 7) * 32 + (bid >> 3);
    const int b   = wg >> 6;
    const int jh  = (wg >> 5) & 1;
    const int i0  = (wg & 31) << 5;
    const int jbase = jh << 9;

    const char* KbB = (const char*)(Kg_ + (long)b * 1048576);
    const char* VbB = (const char*)(Vt  + (long)b * 1048576);
    unsigned short* Pout = (jh == 0) ? P0 : P1;

#define STAGE_K(J0) do { \
    _Pragma("unroll") \
    for (int u = 0; u < 4; u++) { \
        const int jrow = u * 4 + (w >> 1); \
        const int c2 = (((w & 1) << 10) + lane * 16) ^ ((jrow & 7) << 4); \
        GLL16(KbB + (long)((J0) + jrow) * 2048 + c2, Ak + u * 8192 + w * 1024); \
    } } while(0)

#define STAGE_V(J0) do { \
    _Pragma("unroll") \
    for (int u = 0; u < 4; u++) { \
        const int d = u * 256 + w * 32 + (lane >> 1); \
        GLL16(VbB + (long)d * 2048 + (J0) * 2 + ((lane & 1) << 4), Bv + u * 8192 + w * 1024); \
    } } while(0)

    // ---- prologue: zero P pad region (k=16..31 stays 0 forever), load Q frags,
    //      stage K(0), V(0), full drain once.
    {
        unsigned* pw = (unsigned*)Pb;
        #pragma unroll
        for (int r = 0; r < 20; r++) pw[r * 512 + tid] = 0u;
    }
    bf16x8 qf[2][2][2];   // [isub][hh][ks]
    #pragma unroll
    for (int is = 0; is < 2; is++)
        #pragma unroll
        for (int hh = 0; hh < 2; hh++)
            #pragma unroll
            for (int ks = 0; ks < 2; ks++)
                qf[is][hh][ks] = *(const bf16x8*)(Q + (long)(b*1024 + i0 + is*16 + l15) * 1024
                                                  + (h0 + hh) * 64 + ks * 32 + l4 * 8);
    STAGE_K(jbase);
    STAGE_V(jbase);

    f32x4 acc[2][2][4];   // [isub][hh][n]
    #pragma unroll
    for (int is = 0; is < 2; is++)
        #pragma unroll
        for (int hh = 0; hh < 2; hh++)
            #pragma unroll
            for (int n = 0; n < 4; n++)
                acc[is][hh][n] = (f32x4){0.f, 0.f, 0.f, 0.f};

    LGKM0; VM0; BAR;   // K(0), V(0) resident; P zeros visible

#define ITER(T, LASTF) do { \
    const int j0 = jbase + (T) * 16; \
    const int mk = mask[(i0 + (tid >> 4)) * 1024 + j0 + (tid & 15)]; \
    /* ---- QK^T from swizzled K tile ---- */ \
    bf16x8 kf[2][2]; \
    _Pragma("unroll") \
    for (int hh = 0; hh < 2; hh++) \
        _Pragma("unroll") \
        for (int ks = 0; ks < 2; ks++) { \
            const int g = ((h0 + hh) * 128 + ks * 64 + l4 * 16) ^ ((l15 & 7) << 4); \
            kf[hh][ks] = *(const bf16x8*)(Ak + l15 * 2048 + g); \
        } \
    f32x4 sv[2][2]; \
    _Pragma("unroll") \
    for (int is = 0; is < 2; is++) \
        _Pragma("unroll") \
        for (int hh = 0; hh < 2; hh++) { \
            f32x4 s0 = (f32x4){0.f, 0.f, 0.f, 0.f}; \
            s0 = __builtin_amdgcn_mfma_f32_16x16x32_bf16(qf[is][hh][0], kf[hh][0], s0, 0, 0, 0); \
            s0 = __builtin_amdgcn_mfma_f32_16x16x32_bf16(qf[is][hh][1], kf[hh][1], s0, 0, 0, 0); \
            sv[is][hh] = s0; \
        } \
    _Pragma("unroll") \
    for (int is = 0; is < 2; is++) \
        _Pragma("unroll") \
        for (int r = 0; r < 4; r++) \
            _Pragma("unroll") \
            for (int hh = 0; hh < 2; hh++) \
                S[((is*16 + l4*4 + r) * 16 + l15) * 17 + h0 + hh] = sv[is][hh][r]; \
    LGKM0; BAR;                              /* S1: K reads done, scores visible */ \
    if (!(LASTF)) STAGE_K(j0 + 16); \
    /* ---- head-softmax: one thread per (i,j) ---- */ \
    { \
        const int si = tid >> 4, sj = tid & 15; \
        const float* sp = S + (si * 16 + sj) * 17; \
        float sc[16]; float mx = -1e30f; \
        _Pragma("unroll") \
        for (int h = 0; h < 16; h++) { \
            float vv = sp[h] * 0.125f; \
            if (mk == 0) vv = -__builtin_inff(); \
            sc[h] = vv; mx = fmaxf(mx, vv); \
        } \
        float Z = 0.f; \
        _Pragma("unroll") \
        for (int h = 0; h < 16; h++) { const float e = __expf(sc[h] - mx); sc[h] = e; Z += e; } \
        const float inv = 1.f / Z; \
        _Pragma("unroll") \
        for (int h = 0; h < 16; h++) \
            *(unsigned short*)(Pb + h * 2560 + si * 80 + sj * 2) = f2b(sc[h] * inv); \
    } \
    LGKM0; \
    if (LASTF) { VM0; } else { VM4; }        /* V(t) resident */ \
    BAR;                                     /* S2 */ \
    /* ---- PV ---- */ \
    { \
        bf16x8 vf[2][4]; \
        _Pragma("unroll") \
        for (int hh = 0; hh < 2; hh++) \
            _Pragma("unroll") \
            for (int n = 0; n < 4; n++) \
                vf[hh][n] = *(const bf16x8*)(Bv + ((h0 + hh) * 64 + n * 16 + l15) * 32 + (l4 & 1) * 16); \
        bf16x8 pa[2][2]; \
        _Pragma("unroll") \
        for (int is = 0; is < 2; is++) \
            _Pragma("unroll") \
            for (int hh = 0; hh < 2; hh++) \
                pa[is][hh] = *(const bf16x8*)(Pb + (h0 + hh) * 2560 + (is*16 + l15) * 80 + l4 * 16); \
        _Pragma("unroll") \
        for (int is = 0; is < 2; is++) \
            _Pragma("unroll") \
            for (int hh = 0; hh < 2; hh++) \
                _Pragma("unroll") \
                for (int n = 0; n < 4; n++) \
                    acc[is][hh][n] = __builtin_amdgcn_mfma_f32_16x16x32_bf16(pa[is][hh], vf[hh][n], acc[is][hh][n], 0, 0, 0); \
    } \
    LGKM0; BAR;                              /* S3: V reads done */ \
    if (!(LASTF)) { \
        STAGE_V(j0 + 16); \
        VM4; BAR;                            /* S0: K(t+1) resident */ \
    } \
} while(0)

    for (int t = 0; t < 31; t++) ITER(t, 0);
    ITER(31, 1);

    // ---- epilogue: bf16 partial
    #pragma unroll
    for (int is = 0; is < 2; is++)
        #pragma unroll
        for (int hh = 0; hh < 2; hh++)
            #pragma unroll
            for (int n = 0; n < 4; n++)
                #pragma unroll
                for (int r = 0; r < 4; r++) {
                    const long row = b * 1024 + i0 + is * 16 + l4 * 4 + r;
                    Pout[row * 1024 + (h0 + hh) * 64 + n * 16 + l15] = f2b(acc[is][hh][n][r]);
                }
#undef ITER
#undef STAGE_K
#undef STAGE_V
}

// ---------------- reduce: P0 += P1 (bf16, in place) ---------------------------
__global__ __launch_bounds__(256) void addp(
    unsigned short* __restrict__ P0, const unsigned short* __restrict__ P1)
{
    const long i = ((long)blockIdx.x * 256 + threadIdx.x) * 8;
    ushort4 a0 = *(const ushort4*)(P0 + i);
    ushort4 a1 = *(const ushort4*)(P0 + i + 4);
    ushort4 b0 = *(const ushort4*)(P1 + i);
    ushort4 b1 = *(const ushort4*)(P1 + i + 4);
    ushort4 o0, o1;
    o0.x = f2b(b2f(a0.x) + b2f(b0.x)); o0.y = f2b(b2f(a0.y) + b2f(b0.y));
    o0.z = f2b(b2f(a0.z) + b2f(b0.z)); o0.w = f2b(b2f(a0.w) + b2f(b0.w));
    o1.x = f2b(b2f(a1.x) + b2f(b1.x)); o1.y = f2b(b2f(a1.y) + b2f(b1.y));
    o1.z = f2b(b2f(a1.z) + b2f(b1.z)); o1.w = f2b(b2f(a1.w) + b2f(b1.w));
    *(ushort4*)(P0 + i) = o0;
    *(ushort4*)(P0 + i + 4) = o1;
}

extern "C" void kernel_launch(void* const* d_in, const int* in_sizes, int n_in,
                              void* d_out, int out_size, void* d_ws, size_t ws_size,
                              hipStream_t stream)
{
    const float* q    = (const float*)d_in[0];
    const float* k    = (const float*)d_in[1];
    const float* v    = (const float*)d_in[2];
    const int*   mask = (const int*)  d_in[3];
    const float* Wq   = (const float*)d_in[4];
    const float* bq   = (const float*)d_in[5];
    const float* Wk   = (const float*)d_in[6];
    const float* bk   = (const float*)d_in[7];
    const float* Wv   = (const float*)d_in[8];
    const float* bv   = (const float*)d_in[9];
    const float* Wo   = (const float*)d_in[10];
    const float* bo   = (const float*)d_in[11];

    unsigned short* ws = (unsigned short*)d_ws;
    const long MS = 1048576;
    unsigned short* WT  = ws;             // 4 transposed weights      [0,4M)
    unsigned short* Xq  = ws + 4*MS;      // bf16 query  -> later Vt   [4M,8M)
    unsigned short* Xk  = ws + 8*MS;      // bf16 key    -> later P0   [8M,12M)
    unsigned short* Xv  = ws + 12*MS;     // bf16 value                [12M,16M)
    unsigned short* Qm  = ws + 16*MS;     // Q projection              [16M,20M)
    unsigned short* Km  = ws + 20*MS;     // K projection              [20M,24M)
    unsigned short* Vm  = ws + 24*MS;     // V projection -> later P1  [24M,28M)
    unsigned short* Vtm = Xq;
    unsigned short* P0  = Xk;
    unsigned short* P1  = Vm;

    convert_qkv<<<12288, 256, 0, stream>>>(q, k, v, Xq);
    wtrans<<<dim3(32, 32, 4), dim3(32, 8), 0, stream>>>(Wq, Wk, Wv, Wo, WT);
    gemm3<<<dim3(32, 8, 3), 256, 0, stream>>>(Xq, WT, bq, bk, bv, Qm);
    vtrans<<<dim3(32, 32, 4), dim3(32, 8), 0, stream>>>(Vm, Vtm);
    attn_fused<<<256, 512, 0, stream>>>(Qm, Km, Vtm, mask, P0, P1);
    addp<<<2048, 256, 0, stream>>>(P0, P1);
    gemm_bias_f32<<<dim3(32, 8), 256, 0, stream>>>(P0, WT + 3*MS, bo, (float*)d_out, 1024, 1024);
}

// Round 6
// 188.182 us; speedup vs baseline: 1.7609x; 1.0275x over previous
//
#include <hip/hip_runtime.h>
#include <hip/hip_bf16.h>

// B=4, S=1024, D=1024, H=16, DH=64. Softmax over HEADS (per (i,j)), per reference.

using f32x4  = __attribute__((ext_vector_type(4))) float;
using bf16x8 = __attribute__((ext_vector_type(8))) short;

__device__ inline unsigned short f2b(float f){
    unsigned u = __float_as_uint(f);
    unsigned r = (u + 0x7fffu + ((u >> 16) & 1u)) >> 16;
    return (unsigned short)r;
}
__device__ inline float b2f(unsigned short s){
    return __uint_as_float(((unsigned)s) << 16);
}

#define GLL16(gp, lp) __builtin_amdgcn_global_load_lds( \
    (const __attribute__((address_space(1))) void*)(gp), \
    (__attribute__((address_space(3))) void*)(lp), 16, 0, 0)

#define LGKM0 do { asm volatile("s_waitcnt lgkmcnt(0)" ::: "memory"); \
                   __builtin_amdgcn_sched_barrier(0); } while(0)
#define VM4   do { asm volatile("s_waitcnt vmcnt(4)" ::: "memory"); \
                   __builtin_amdgcn_sched_barrier(0); } while(0)
#define VM0   do { asm volatile("s_waitcnt vmcnt(0)" ::: "memory"); \
                   __builtin_amdgcn_sched_barrier(0); } while(0)
#define BAR   do { __builtin_amdgcn_s_barrier(); \
                   __builtin_amdgcn_sched_barrier(0); } while(0)
#define SCHED do { __builtin_amdgcn_sched_barrier(0); } while(0)

// ---------------- convert q,k,v f32 -> bf16, contiguous [3][4096][1024] -------
__global__ __launch_bounds__(256) void convert_qkv(
    const float* __restrict__ q, const float* __restrict__ k, const float* __restrict__ v,
    unsigned short* __restrict__ dst)
{
    const long gid = (long)blockIdx.x * 256 + threadIdx.x;
    const int  t   = (int)(gid >> 20);
    const long off = (gid & 1048575) << 2;
    const float* src = (t == 0) ? q : (t == 1) ? k : v;
    const float4 x = *(const float4*)(src + off);
    ushort4 o;
    o.x = f2b(x.x); o.y = f2b(x.y); o.z = f2b(x.z); o.w = f2b(x.w);
    *(ushort4*)(dst + (long)t * 4194304 + off) = o;
}

// ---------------- transpose+convert W f32 [k][n] -> bf16 [n][k] ---------------
__global__ __launch_bounds__(256) void wtrans(
    const float* __restrict__ w0, const float* __restrict__ w1,
    const float* __restrict__ w2, const float* __restrict__ w3,
    unsigned short* __restrict__ out)
{
    const float* W = (blockIdx.z == 0) ? w0 : (blockIdx.z == 1) ? w1 : (blockIdx.z == 2) ? w2 : w3;
    unsigned short* O = out + (long)blockIdx.z * 1048576;
    __shared__ float t[32][33];
    const int n0 = blockIdx.x * 32, k0 = blockIdx.y * 32;
    const int tx = threadIdx.x, ty = threadIdx.y;
    #pragma unroll
    for (int i = 0; i < 4; i++)
        t[ty + 8*i][tx] = W[(long)(k0 + ty + 8*i) * 1024 + n0 + tx];
    __syncthreads();
    #pragma unroll
    for (int i = 0; i < 4; i++)
        O[(long)(n0 + ty + 8*i) * 1024 + k0 + tx] = f2b(t[tx][ty + 8*i]);
}

// ---------------- transpose V bf16 [b*1024+s][d] -> Vt [b][d][s] --------------
__global__ __launch_bounds__(256) void vtrans(
    const unsigned short* __restrict__ V, unsigned short* __restrict__ Vt)
{
    const int b = blockIdx.z;
    __shared__ unsigned short t[32][33];
    const int s0 = blockIdx.x * 32, d0 = blockIdx.y * 32;
    const int tx = threadIdx.x, ty = threadIdx.y;
    #pragma unroll
    for (int i = 0; i < 4; i++)
        t[ty + 8*i][tx] = V[(long)(b*1024 + s0 + ty + 8*i) * 1024 + d0 + tx];
    __syncthreads();
    #pragma unroll
    for (int i = 0; i < 4; i++)
        Vt[(long)b * 1048576 + (long)(d0 + ty + 8*i) * 1024 + s0 + tx] = t[tx][ty + 8*i];
}

// ---------------- GEMM tile body (m97 structure) ------------------------------
template<int OUTF32>
__device__ __forceinline__ void gemm_body(
    const unsigned short* __restrict__ A,
    const unsigned short* __restrict__ BT,
    const float* __restrict__ bias,
    void* __restrict__ Cout, int N, int K,
    unsigned short* As, unsigned short* Bs)
{
    const int tid  = threadIdx.x;
    const int wave = tid >> 6, lane = tid & 63;
    const int l15  = lane & 15, l4 = lane >> 4;
    const int wr   = wave >> 1, wc = wave & 1;
    const long rowBase = (long)blockIdx.x * 128;
    const long colBase = (long)blockIdx.y * 128;

    f32x4 acc[4][4];
    #pragma unroll
    for (int m = 0; m < 4; m++)
        #pragma unroll
        for (int n = 0; n < 4; n++)
            acc[m][n] = (f32x4){0.f, 0.f, 0.f, 0.f};

    const int c0    = wave * 2;
    const int srow0 = c0 * 16 + (lane >> 2);
    const int srow1 = srow0 + 16;
    const int skk   = (lane & 3) * 8;

    for (int k0 = 0; k0 < K; k0 += 32) {
        GLL16(A  + (rowBase + srow0) * K + k0 + skk, As + c0 * 512);
        GLL16(A  + (rowBase + srow1) * K + k0 + skk, As + (c0 + 1) * 512);
        GLL16(BT + (colBase + srow0) * K + k0 + skk, Bs + c0 * 512);
        GLL16(BT + (colBase + srow1) * K + k0 + skk, Bs + (c0 + 1) * 512);
        __syncthreads();
        bf16x8 af[4], bfr[4];
        #pragma unroll
        for (int m = 0; m < 4; m++)
            af[m] = *(const bf16x8*)(As + (wr*64 + m*16 + l15) * 32 + l4 * 8);
        #pragma unroll
        for (int n = 0; n < 4; n++)
            bfr[n] = *(const bf16x8*)(Bs + (wc*64 + n*16 + l15) * 32 + l4 * 8);
        #pragma unroll
        for (int m = 0; m < 4; m++)
            #pragma unroll
            for (int n = 0; n < 4; n++)
                acc[m][n] = __builtin_amdgcn_mfma_f32_16x16x32_bf16(af[m], bfr[n], acc[m][n], 0, 0, 0);
        __syncthreads();
    }

    #pragma unroll
    for (int m = 0; m < 4; m++) {
        const long row = rowBase + wr*64 + m*16 + l4*4;
        #pragma unroll
        for (int n = 0; n < 4; n++) {
            const long col = colBase + wc*64 + n*16 + l15;
            const float bv = bias[col];
            #pragma unroll
            for (int r = 0; r < 4; r++) {
                const float vv = acc[m][n][r] + bv;
                if (OUTF32) ((float*)Cout)[(row + r) * N + col] = vv;
                else        ((unsigned short*)Cout)[(row + r) * N + col] = f2b(vv);
            }
        }
    }
}

__global__ __launch_bounds__(256) void gemm_bias_f32(
    const unsigned short* __restrict__ A,
    const unsigned short* __restrict__ BT,
    const float* __restrict__ bias,
    float* __restrict__ Cout, int N, int K)
{
    __shared__ unsigned short As[128 * 32];
    __shared__ unsigned short Bs[128 * 32];
    gemm_body<1>(A, BT, bias, (void*)Cout, N, K, As, Bs);
}

__global__ __launch_bounds__(256) void gemm3(
    const unsigned short* __restrict__ Abase,
    const unsigned short* __restrict__ WT,
    const float* __restrict__ bq, const float* __restrict__ bk, const float* __restrict__ bv,
    unsigned short* __restrict__ Cbase)
{
    __shared__ unsigned short As[128 * 32];
    __shared__ unsigned short Bs[128 * 32];
    const int z = blockIdx.z;
    const unsigned short* A  = Abase + (long)z * 4194304;
    const unsigned short* BT = WT    + (long)z * 1048576;
    unsigned short*       C  = Cbase + (long)z * 4194304;
    const float* bias = (z == 0) ? bq : (z == 1) ? bk : bv;
    gemm_body<0>(A, BT, bias, (void*)C, 1024, 1024, As, Bs);
}

// ---------------- fused attention ---------------------------------------------
// IBLK=32 i-rows, KVBLK=16 j-cols per iter, 32 iters over a 512-j half.
// 3 barriers/iter. Every vm-wait is followed by a barrier before any
// cross-wave LDS read (fixes the round-5 race):
//   QK(K(t)) | S1 | stageK(t+1), softmax, VM4(V(t) ready) | S2 |
//   PV(V(t)) | VM0(K(t+1) ready) | S3 | stageV(t+1)
__global__ __launch_bounds__(512) void attn_fused(
    const unsigned short* __restrict__ Q,    // [4096][1024]
    const unsigned short* __restrict__ Kg_,  // [4096][1024]
    const unsigned short* __restrict__ Vt,   // [4][1024(d)][1024(s)]
    const int* __restrict__ mask,            // [1024*1024]
    unsigned short* __restrict__ P0,
    unsigned short* __restrict__ P1)
{
    __shared__ __align__(16) unsigned char smem[147456];
    unsigned char* Ak = smem;                       // 32768: K tile [j16][128 sw-chunks]
    unsigned char* Bv = smem + 32768;               // 32768: V tile [d1024][j 2 chunks]
    float*          S = (float*)(smem + 65536);     // 40960: [ij(512)][20] f32, h-xor layout
    unsigned char* Pb = smem + 106496;              // 40960: [h16][i32][40B j] bf16

    const int tid = threadIdx.x, w = tid >> 6, lane = tid & 63;
    const int l15 = lane & 15, l4 = lane >> 4;
    const int h0 = 2 * w;

    // bijective XCD swizzle: 256 blocks -> 32 consecutive wg per XCD
    const int bid = blockIdx.x;
    const int wg  = (bid & 7) * 32 + (bid >> 3);
    const int b   = wg >> 6;
    const int jh  = (wg >> 5) & 1;
    const int i0  = (wg & 31) << 5;
    const int jbase = jh << 9;

    const char* KbB = (const char*)(Kg_ + (long)b * 1048576);
    const char* VbB = (const char*)(Vt  + (long)b * 1048576);
    unsigned short* Pout = (jh == 0) ? P0 : P1;

#define STAGE_K(J0) do { \
    _Pragma("unroll") \
    for (int u = 0; u < 4; u++) { \
        const int jrow = u * 4 + (w >> 1); \
        const int c2 = (((w & 1) << 10) + lane * 16) ^ ((jrow & 7) << 4); \
        GLL16(KbB + (long)((J0) + jrow) * 2048 + c2, Ak + u * 8192 + w * 1024); \
    } } while(0)

#define STAGE_V(J0) do { \
    _Pragma("unroll") \
    for (int u = 0; u < 4; u++) { \
        const int d = u * 256 + w * 32 + (lane >> 1); \
        GLL16(VbB + (long)d * 2048 + (J0) * 2 + ((lane & 1) << 4), Bv + u * 8192 + w * 1024); \
    } } while(0)

    // ---- prologue: zero Pb (pad k=16..31 stays 0), Q frags, stage K(0),V(0)
    {
        unsigned* pw = (unsigned*)Pb;
        #pragma unroll
        for (int r = 0; r < 20; r++) pw[r * 512 + tid] = 0u;
    }
    bf16x8 qf[2][2][2];   // [isub][hh][ks]
    #pragma unroll
    for (int is = 0; is < 2; is++)
        #pragma unroll
        for (int hh = 0; hh < 2; hh++)
            #pragma unroll
            for (int ks = 0; ks < 2; ks++)
                qf[is][hh][ks] = *(const bf16x8*)(Q + (long)(b*1024 + i0 + is*16 + l15) * 1024
                                                  + (h0 + hh) * 64 + ks * 32 + l4 * 8);
    SCHED;            // keep Q loads (8) ahead of the GLL queue
    STAGE_K(jbase);   // +4
    STAGE_V(jbase);   // +4
    VM4;              // drains Q + K(0), leaves V(0) in flight
    BAR;              // K(0) visible to all waves

    f32x4 acc[2][2][4];   // [isub][hh][n]
    #pragma unroll
    for (int is = 0; is < 2; is++)
        #pragma unroll
        for (int hh = 0; hh < 2; hh++)
            #pragma unroll
            for (int n = 0; n < 4; n++)
                acc[is][hh][n] = (f32x4){0.f, 0.f, 0.f, 0.f};

#define ITER(T, LASTF) do { \
    const int j0 = jbase + (T) * 16; \
    const int mk = mask[(i0 + (tid >> 4)) * 1024 + j0 + (tid & 15)]; \
    /* ---- QK^T from swizzled K tile (resident per prologue / prior S3) ---- */ \
    { \
        bf16x8 kf[2][2]; \
        _Pragma("unroll") \
        for (int hh = 0; hh < 2; hh++) \
            _Pragma("unroll") \
            for (int ks = 0; ks < 2; ks++) { \
                const int g = ((h0 + hh) * 128 + ks * 64 + l4 * 16) ^ ((l15 & 7) << 4); \
                kf[hh][ks] = *(const bf16x8*)(Ak + l15 * 2048 + g); \
            } \
        _Pragma("unroll") \
        for (int is = 0; is < 2; is++) { \
            f32x4 sv0 = (f32x4){0.f,0.f,0.f,0.f}, sv1 = (f32x4){0.f,0.f,0.f,0.f}; \
            sv0 = __builtin_amdgcn_mfma_f32_16x16x32_bf16(qf[is][0][0], kf[0][0], sv0, 0, 0, 0); \
            sv0 = __builtin_amdgcn_mfma_f32_16x16x32_bf16(qf[is][0][1], kf[0][1], sv0, 0, 0, 0); \
            sv1 = __builtin_amdgcn_mfma_f32_16x16x32_bf16(qf[is][1][0], kf[1][0], sv1, 0, 0, 0); \
            sv1 = __builtin_amdgcn_mfma_f32_16x16x32_bf16(qf[is][1][1], kf[1][1], sv1, 0, 0, 0); \
            _Pragma("unroll") \
            for (int r = 0; r < 4; r++) { \
                const int ij = (is*16 + l4*4 + r) * 16 + l15; \
                float2 pr; pr.x = sv0[r]; pr.y = sv1[r]; \
                *(float2*)(S + ij * 20 + (h0 ^ (l4 << 2))) = pr; \
            } \
        } \
    } \
    LGKM0; BAR;                              /* S1: K consumed, S visible */ \
    if (!(LASTF)) STAGE_K(j0 + 16); \
    /* ---- head-softmax: one thread per (i,j), b128 S reads, xor-h order ---- */ \
    { \
        const int si = tid >> 4, sj = tid & 15; \
        const int xorv = (w & 3) << 2; \
        const float* sp = S + tid * 20; \
        float tv[16]; \
        _Pragma("unroll") \
        for (int qd = 0; qd < 4; qd++) { \
            const f32x4 t4 = *(const f32x4*)(sp + qd * 4); \
            tv[qd*4+0] = t4[0]; tv[qd*4+1] = t4[1]; tv[qd*4+2] = t4[2]; tv[qd*4+3] = t4[3]; \
        } \
        float mx = -3.0e38f; \
        _Pragma("unroll") \
        for (int h = 0; h < 16; h++) { \
            float x = tv[h] * 0.18033688f;   /* 0.125 * log2(e) */ \
            if (mk == 0) x = -__builtin_inff(); \
            tv[h] = x; mx = fmaxf(mx, x); \
        } \
        float Z = 0.f; \
        _Pragma("unroll") \
        for (int h = 0; h < 16; h++) { \
            float e; const float xa = tv[h] - mx; \
            asm("v_exp_f32 %0, %1" : "=v"(e) : "v"(xa)); \
            tv[h] = e; Z += e; \
        } \
        float inv; \
        asm("v_rcp_f32 %0, %1" : "=v"(inv) : "v"(Z)); \
        _Pragma("unroll") \
        for (int h = 0; h < 16; h++) { \
            const int origh = h ^ xorv; \
            *(unsigned short*)(Pb + origh * 2560 + si * 80 + sj * 2) = f2b(tv[h] * inv); \
        } \
    } \
    LGKM0; \
    if (LASTF) { VM0; } else { VM4; }        /* V(t) resident (leaves K(t+1)) */ \
    BAR;                                     /* S2: P visible, V ready */ \
    /* ---- PV ---- */ \
    { \
        bf16x8 vf[2][4]; \
        _Pragma("unroll") \
        for (int hh = 0; hh < 2; hh++) \
            _Pragma("unroll") \
            for (int n = 0; n < 4; n++) \
                vf[hh][n] = *(const bf16x8*)(Bv + ((h0 + hh) * 64 + n * 16 + l15) * 32 + (l4 & 1) * 16); \
        bf16x8 pa[2][2]; \
        _Pragma("unroll") \
        for (int is = 0; is < 2; is++) \
            _Pragma("unroll") \
            for (int hh = 0; hh < 2; hh++) \
                pa[is][hh] = *(const bf16x8*)(Pb + (h0 + hh) * 2560 + (is*16 + l15) * 80 + l4 * 16); \
        _Pragma("unroll") \
        for (int is = 0; is < 2; is++) \
            _Pragma("unroll") \
            for (int hh = 0; hh < 2; hh++) \
                _Pragma("unroll") \
                for (int n = 0; n < 4; n++) \
                    acc[is][hh][n] = __builtin_amdgcn_mfma_f32_16x16x32_bf16(pa[is][hh], vf[hh][n], acc[is][hh][n], 0, 0, 0); \
    } \
    LGKM0; \
    if (!(LASTF)) { VM0; }                   /* K(t+1) resident */ \
    BAR;                                     /* S3: V consumed, K(t+1) visible */ \
    if (!(LASTF)) STAGE_V(j0 + 16); \
} while(0)

    for (int t = 0; t < 31; t++) ITER(t, 0);
    ITER(31, 1);

    // ---- epilogue: bf16 partial
    #pragma unroll
    for (int is = 0; is < 2; is++)
        #pragma unroll
        for (int hh = 0; hh < 2; hh++)
            #pragma unroll
            for (int n = 0; n < 4; n++)
                #pragma unroll
                for (int r = 0; r < 4; r++) {
                    const long row = b * 1024 + i0 + is * 16 + l4 * 4 + r;
                    Pout[row * 1024 + (h0 + hh) * 64 + n * 16 + l15] = f2b(acc[is][hh][n][r]);
                }
#undef ITER
#undef STAGE_K
#undef STAGE_V
}

// ---------------- reduce: P0 += P1 (bf16, in place) ---------------------------
__global__ __launch_bounds__(256) void addp(
    unsigned short* __restrict__ P0, const unsigned short* __restrict__ P1)
{
    const long i = ((long)blockIdx.x * 256 + threadIdx.x) * 8;
    ushort4 a0 = *(const ushort4*)(P0 + i);
    ushort4 a1 = *(const ushort4*)(P0 + i + 4);
    ushort4 b0 = *(const ushort4*)(P1 + i);
    ushort4 b1 = *(const ushort4*)(P1 + i + 4);
    ushort4 o0, o1;
    o0.x = f2b(b2f(a0.x) + b2f(b0.x)); o0.y = f2b(b2f(a0.y) + b2f(b0.y));
    o0.z = f2b(b2f(a0.z) + b2f(b0.z)); o0.w = f2b(b2f(a0.w) + b2f(b0.w));
    o1.x = f2b(b2f(a1.x) + b2f(b1.x)); o1.y = f2b(b2f(a1.y) + b2f(b1.y));
    o1.z = f2b(b2f(a1.z) + b2f(b1.z)); o1.w = f2b(b2f(a1.w) + b2f(b1.w));
    *(ushort4*)(P0 + i) = o0;
    *(ushort4*)(P0 + i + 4) = o1;
}

extern "C" void kernel_launch(void* const* d_in, const int* in_sizes, int n_in,
                              void* d_out, int out_size, void* d_ws, size_t ws_size,
                              hipStream_t stream)
{
    const float* q    = (const float*)d_in[0];
    const float* k    = (const float*)d_in[1];
    const float* v    = (const float*)d_in[2];
    const int*   mask = (const int*)  d_in[3];
    const float* Wq   = (const float*)d_in[4];
    const float* bq   = (const float*)d_in[5];
    const float* Wk   = (const float*)d_in[6];
    const float* bk   = (const float*)d_in[7];
    const float* Wv   = (const float*)d_in[8];
    const float* bv   = (const float*)d_in[9];
    const float* Wo   = (const float*)d_in[10];
    const float* bo   = (const float*)d_in[11];

    unsigned short* ws = (unsigned short*)d_ws;
    const long MS = 1048576;
    unsigned short* WT  = ws;             // 4 transposed weights      [0,4M)
    unsigned short* Xq  = ws + 4*MS;      // bf16 query  -> later Vt   [4M,8M)
    unsigned short* Xk  = ws + 8*MS;      // bf16 key    -> later P0   [8M,12M)
    unsigned short* Xv  = ws + 12*MS;     // bf16 value                [12M,16M)
    unsigned short* Qm  = ws + 16*MS;     // Q projection              [16M,20M)
    unsigned short* Km  = ws + 20*MS;     // K projection              [20M,24M)
    unsigned short* Vm  = ws + 24*MS;     // V projection -> later P1  [24M,28M)
    unsigned short* Vtm = Xq;
    unsigned short* P0  = Xk;
    unsigned short* P1  = Vm;

    convert_qkv<<<12288, 256, 0, stream>>>(q, k, v, Xq);
    wtrans<<<dim3(32, 32, 4), dim3(32, 8), 0, stream>>>(Wq, Wk, Wv, Wo, WT);
    gemm3<<<dim3(32, 8, 3), 256, 0, stream>>>(Xq, WT, bq, bk, bv, Qm);
    vtrans<<<dim3(32, 32, 4), dim3(32, 8), 0, stream>>>(Vm, Vtm);
    attn_fused<<<256, 512, 0, stream>>>(Qm, Km, Vtm, mask, P0, P1);
    addp<<<2048, 256, 0, stream>>>(P0, P1);
    gemm_bias_f32<<<dim3(32, 8), 256, 0, stream>>>(P0, WT + 3*MS, bo, (float*)d_out, 1024, 1024);
}

// Round 7
// 169.175 us; speedup vs baseline: 1.9588x; 1.1124x over previous
//
#include <hip/hip_runtime.h>
#include <hip/hip_bf16.h>

// B=4, S=1024, D=1024, H=16, DH=64. Softmax over HEADS (per (i,j)), per reference.

using f32x4  = __attribute__((ext_vector_type(4))) float;
using bf16x8 = __attribute__((ext_vector_type(8))) short;

__device__ inline unsigned short f2b(float f){
    unsigned u = __float_as_uint(f);
    unsigned r = (u + 0x7fffu + ((u >> 16) & 1u)) >> 16;
    return (unsigned short)r;
}
__device__ inline float b2f(unsigned short s){
    return __uint_as_float(((unsigned)s) << 16);
}

#define GLL16(gp, lp) __builtin_amdgcn_global_load_lds( \
    (const __attribute__((address_space(1))) void*)(gp), \
    (__attribute__((address_space(3))) void*)(lp), 16, 0, 0)

#define LGKM0 do { asm volatile("s_waitcnt lgkmcnt(0)" ::: "memory"); \
                   __builtin_amdgcn_sched_barrier(0); } while(0)
#define BAR   do { __builtin_amdgcn_s_barrier(); \
                   __builtin_amdgcn_sched_barrier(0); } while(0)

// ---------------- convert q,k,v f32 -> bf16, contiguous [3][4096][1024] -------
__global__ __launch_bounds__(256) void convert_qkv(
    const float* __restrict__ q, const float* __restrict__ k, const float* __restrict__ v,
    unsigned short* __restrict__ dst)
{
    const long gid = (long)blockIdx.x * 256 + threadIdx.x;
    const int  t   = (int)(gid >> 20);
    const long off = (gid & 1048575) << 2;
    const float* src = (t == 0) ? q : (t == 1) ? k : v;
    const float4 x = *(const float4*)(src + off);
    ushort4 o;
    o.x = f2b(x.x); o.y = f2b(x.y); o.z = f2b(x.z); o.w = f2b(x.w);
    *(ushort4*)(dst + (long)t * 4194304 + off) = o;
}

// ---------------- transpose+convert W f32 [k][n] -> bf16 [n][k] ---------------
__global__ __launch_bounds__(256) void wtrans(
    const float* __restrict__ w0, const float* __restrict__ w1,
    const float* __restrict__ w2, const float* __restrict__ w3,
    unsigned short* __restrict__ out)
{
    const float* W = (blockIdx.z == 0) ? w0 : (blockIdx.z == 1) ? w1 : (blockIdx.z == 2) ? w2 : w3;
    unsigned short* O = out + (long)blockIdx.z * 1048576;
    __shared__ float t[32][33];
    const int n0 = blockIdx.x * 32, k0 = blockIdx.y * 32;
    const int tx = threadIdx.x, ty = threadIdx.y;
    #pragma unroll
    for (int i = 0; i < 4; i++)
        t[ty + 8*i][tx] = W[(long)(k0 + ty + 8*i) * 1024 + n0 + tx];
    __syncthreads();
    #pragma unroll
    for (int i = 0; i < 4; i++)
        O[(long)(n0 + ty + 8*i) * 1024 + k0 + tx] = f2b(t[tx][ty + 8*i]);
}

// ---------------- transpose V bf16 [b*1024+s][d] -> Vt [b][d][s] --------------
__global__ __launch_bounds__(256) void vtrans(
    const unsigned short* __restrict__ V, unsigned short* __restrict__ Vt)
{
    const int b = blockIdx.z;
    __shared__ unsigned short t[32][33];
    const int s0 = blockIdx.x * 32, d0 = blockIdx.y * 32;
    const int tx = threadIdx.x, ty = threadIdx.y;
    #pragma unroll
    for (int i = 0; i < 4; i++)
        t[ty + 8*i][tx] = V[(long)(b*1024 + s0 + ty + 8*i) * 1024 + d0 + tx];
    __syncthreads();
    #pragma unroll
    for (int i = 0; i < 4; i++)
        Vt[(long)b * 1048576 + (long)(d0 + ty + 8*i) * 1024 + s0 + tx] = t[tx][ty + 8*i];
}

// ---------------- GEMM tile body (m97 structure) ------------------------------
template<int OUTF32>
__device__ __forceinline__ void gemm_body(
    const unsigned short* __restrict__ A,
    const unsigned short* __restrict__ BT,
    const float* __restrict__ bias,
    void* __restrict__ Cout, int N, int K,
    unsigned short* As, unsigned short* Bs)
{
    const int tid  = threadIdx.x;
    const int wave = tid >> 6, lane = tid & 63;
    const int l15  = lane & 15, l4 = lane >> 4;
    const int wr   = wave >> 1, wc = wave & 1;
    const long rowBase = (long)blockIdx.x * 128;
    const long colBase = (long)blockIdx.y * 128;

    f32x4 acc[4][4];
    #pragma unroll
    for (int m = 0; m < 4; m++)
        #pragma unroll
        for (int n = 0; n < 4; n++)
            acc[m][n] = (f32x4){0.f, 0.f, 0.f, 0.f};

    const int c0    = wave * 2;
    const int srow0 = c0 * 16 + (lane >> 2);
    const int srow1 = srow0 + 16;
    const int skk   = (lane & 3) * 8;

    for (int k0 = 0; k0 < K; k0 += 32) {
        GLL16(A  + (rowBase + srow0) * K + k0 + skk, As + c0 * 512);
        GLL16(A  + (rowBase + srow1) * K + k0 + skk, As + (c0 + 1) * 512);
        GLL16(BT + (colBase + srow0) * K + k0 + skk, Bs + c0 * 512);
        GLL16(BT + (colBase + srow1) * K + k0 + skk, Bs + (c0 + 1) * 512);
        __syncthreads();
        bf16x8 af[4], bfr[4];
        #pragma unroll
        for (int m = 0; m < 4; m++)
            af[m] = *(const bf16x8*)(As + (wr*64 + m*16 + l15) * 32 + l4 * 8);
        #pragma unroll
        for (int n = 0; n < 4; n++)
            bfr[n] = *(const bf16x8*)(Bs + (wc*64 + n*16 + l15) * 32 + l4 * 8);
        #pragma unroll
        for (int m = 0; m < 4; m++)
            #pragma unroll
            for (int n = 0; n < 4; n++)
                acc[m][n] = __builtin_amdgcn_mfma_f32_16x16x32_bf16(af[m], bfr[n], acc[m][n], 0, 0, 0);
        __syncthreads();
    }

    #pragma unroll
    for (int m = 0; m < 4; m++) {
        const long row = rowBase + wr*64 + m*16 + l4*4;
        #pragma unroll
        for (int n = 0; n < 4; n++) {
            const long col = colBase + wc*64 + n*16 + l15;
            const float bv = bias[col];
            #pragma unroll
            for (int r = 0; r < 4; r++) {
                const float vv = acc[m][n][r] + bv;
                if (OUTF32) ((float*)Cout)[(row + r) * N + col] = vv;
                else        ((unsigned short*)Cout)[(row + r) * N + col] = f2b(vv);
            }
        }
    }
}

__global__ __launch_bounds__(256) void gemm_bias_f32(
    const unsigned short* __restrict__ A,
    const unsigned short* __restrict__ BT,
    const float* __restrict__ bias,
    float* __restrict__ Cout, int N, int K)
{
    __shared__ unsigned short As[128 * 32];
    __shared__ unsigned short Bs[128 * 32];
    gemm_body<1>(A, BT, bias, (void*)Cout, N, K, As, Bs);
}

__global__ __launch_bounds__(256) void gemm3(
    const unsigned short* __restrict__ Abase,
    const unsigned short* __restrict__ WT,
    const float* __restrict__ bq, const float* __restrict__ bk, const float* __restrict__ bv,
    unsigned short* __restrict__ Cbase)
{
    __shared__ unsigned short As[128 * 32];
    __shared__ unsigned short Bs[128 * 32];
    const int z = blockIdx.z;
    const unsigned short* A  = Abase + (long)z * 4194304;
    const unsigned short* BT = WT    + (long)z * 1048576;
    unsigned short*       C  = Cbase + (long)z * 4194304;
    const float* bias = (z == 0) ? bq : (z == 1) ? bk : bv;
    gemm_body<0>(A, BT, bias, (void*)C, 1024, 1024, As, Bs);
}

// ---------------- fused attention ---------------------------------------------
// IBLK=32 i-rows; GROUP = 32 j-cols; 16 groups over a 512-j half.
// No K/V LDS staging: kf/vf fragments load global->reg (L2-resident; each
// wave's slices are disjoint -> LDS staging had zero cross-wave reuse).
// LDS holds only the cross-wave S (dbuf e/o) and P exchange buffers.
// 2 barriers per group: QK(e)+QK(o) | BAR | softmax(e,o) | BAR | PV (K=32).
__global__ __launch_bounds__(512, 2) void attn_fused(
    const unsigned short* __restrict__ Q,    // [4096][1024]
    const unsigned short* __restrict__ Kg_,  // [4096][1024]
    const unsigned short* __restrict__ Vt,   // [4][1024(d)][1024(s)]
    const int* __restrict__ mask,            // [1024*1024]
    unsigned short* __restrict__ P0,
    unsigned short* __restrict__ P1)
{
    __shared__ __align__(16) unsigned char smem[122880];
    float*         Se = (float*)smem;                 // [512 ij][20 f32]
    float*         So = (float*)(smem + 40960);       // [512 ij][20 f32]
    unsigned char* Pb = smem + 81920;                 // [16 h][32 i][80B: 32j + pad]

    const int tid = threadIdx.x, w = tid >> 6, lane = tid & 63;
    const int l15 = lane & 15, l4 = lane >> 4;
    const int h0  = 2 * w;
    const int sxor = h0 ^ (l4 << 2);

    // bijective XCD swizzle: 256 blocks -> 32 consecutive wg per XCD
    const int bid = blockIdx.x;
    const int wg  = (bid & 7) * 32 + (bid >> 3);
    const int b   = wg >> 6;
    const int jh  = (wg >> 5) & 1;
    const int i0  = (wg & 31) << 5;
    const int jbase = jh << 9;

    const unsigned short* Kb = Kg_ + (long)b * 1048576;
    const unsigned short* Vb = Vt  + (long)b * 1048576;
    unsigned short* Pout = (jh == 0) ? P0 : P1;

    const int si = tid >> 4, sj = tid & 15;    // softmax thread -> (i row, j col)
    const int xorv = si & 12;                  // un-permutes the S h-slots
    const int mrow = (i0 + si) * 1024 + jbase;

    // ---- Q fragments (persistent)
    bf16x8 qf[2][2][2];   // [isub][hh][ks]
    #pragma unroll
    for (int is = 0; is < 2; is++)
        #pragma unroll
        for (int hh = 0; hh < 2; hh++)
            #pragma unroll
            for (int ks = 0; ks < 2; ks++)
                qf[is][hh][ks] = *(const bf16x8*)(Q + (long)(b*1024 + i0 + is*16 + l15) * 1024
                                                  + (h0 + hh) * 64 + ks * 32 + l4 * 8);

#define LOAD_KF(J0) do { \
    _Pragma("unroll") \
    for (int t_ = 0; t_ < 2; t_++) \
        _Pragma("unroll") \
        for (int hh = 0; hh < 2; hh++) \
            _Pragma("unroll") \
            for (int ks = 0; ks < 2; ks++) \
                kf[t_][hh][ks] = *(const bf16x8*)(Kb + (long)((J0) + t_*16 + l15) * 1024 \
                                                   + (h0 + hh) * 64 + ks * 32 + l4 * 8); \
    } while(0)

#define LOAD_VF(J0) do { \
    _Pragma("unroll") \
    for (int hh = 0; hh < 2; hh++) \
        _Pragma("unroll") \
        for (int n = 0; n < 4; n++) \
            vf[hh][n] = *(const bf16x8*)(Vb + (long)((h0 + hh) * 64 + n * 16 + l15) * 1024 \
                                           + (J0) + l4 * 8); \
    } while(0)

    bf16x8 kf[2][2][2];   // [tile e/o][hh][ks]
    bf16x8 vf[2][4];      // [hh][n]
    LOAD_KF(jbase);
    LOAD_VF(jbase);

    f32x4 acc[2][2][4];   // [isub][hh][n]
    #pragma unroll
    for (int is = 0; is < 2; is++)
        #pragma unroll
        for (int hh = 0; hh < 2; hh++)
            #pragma unroll
            for (int n = 0; n < 4; n++)
                acc[is][hh][n] = (f32x4){0.f, 0.f, 0.f, 0.f};

    for (int g = 0; g < 16; ++g) {
        const int j0 = jbase + g * 32;
        const int mke = mask[mrow + g * 32 + sj];
        const int mko = mask[mrow + g * 32 + 16 + sj];

        // ---- QK^T for both tiles (kf in regs; compiler inserts the vm waits)
        #pragma unroll
        for (int t_ = 0; t_ < 2; t_++) {
            float* St = t_ ? So : Se;
            #pragma unroll
            for (int is = 0; is < 2; is++) {
                f32x4 sv0 = (f32x4){0.f,0.f,0.f,0.f}, sv1 = (f32x4){0.f,0.f,0.f,0.f};
                sv0 = __builtin_amdgcn_mfma_f32_16x16x32_bf16(qf[is][0][0], kf[t_][0][0], sv0, 0, 0, 0);
                sv0 = __builtin_amdgcn_mfma_f32_16x16x32_bf16(qf[is][0][1], kf[t_][0][1], sv0, 0, 0, 0);
                sv1 = __builtin_amdgcn_mfma_f32_16x16x32_bf16(qf[is][1][0], kf[t_][1][0], sv1, 0, 0, 0);
                sv1 = __builtin_amdgcn_mfma_f32_16x16x32_bf16(qf[is][1][1], kf[t_][1][1], sv1, 0, 0, 0);
                #pragma unroll
                for (int r = 0; r < 4; r++) {
                    const int ij = (is*16 + l4*4 + r) * 16 + l15;
                    float2 pr; pr.x = sv0[r]; pr.y = sv1[r];
                    *(float2*)(St + ij * 20 + sxor) = pr;
                }
            }
        }
        LGKM0; BAR;                      // S_e, S_o visible

        if (g < 15) LOAD_KF(j0 + 32);    // kf consumed -> refill for g+1

        // ---- head-softmax, both tiles: thread = one (i,j), 16 heads in regs
        #pragma unroll
        for (int t_ = 0; t_ < 2; t_++) {
            const float* sp = (t_ ? So : Se) + (si * 16 + sj) * 20;
            const int    mk = t_ ? mko : mke;
            const int    jc = t_ * 16 + sj;
            float tv[16];
            #pragma unroll
            for (int qd = 0; qd < 4; qd++) {
                const f32x4 t4 = *(const f32x4*)(sp + qd * 4);
                tv[qd*4+0] = t4[0]; tv[qd*4+1] = t4[1];
                tv[qd*4+2] = t4[2]; tv[qd*4+3] = t4[3];
            }
            float mx = -3.0e38f;
            #pragma unroll
            for (int h = 0; h < 16; h++) {
                float x = tv[h] * 0.18033688f;   // 0.125 * log2(e)
                if (mk == 0) x = -__builtin_inff();
                tv[h] = x; mx = fmaxf(mx, x);
            }
            float Z = 0.f;
            #pragma unroll
            for (int h = 0; h < 16; h++) {
                float e; const float xa = tv[h] - mx;
                asm("v_exp_f32 %0, %1" : "=v"(e) : "v"(xa));
                tv[h] = e; Z += e;
            }
            float inv;
            asm("v_rcp_f32 %0, %1" : "=v"(inv) : "v"(Z));
            #pragma unroll
            for (int h = 0; h < 16; h++) {
                const int origh = h ^ xorv;
                *(unsigned short*)(Pb + origh * 2560 + si * 80 + jc * 2) = f2b(tv[h] * inv);
            }
        }
        LGKM0; BAR;                      // P visible

        // ---- PV, full K=32 over the 32-j group (vf in regs)
        {
            bf16x8 pa[2][2];
            #pragma unroll
            for (int is = 0; is < 2; is++)
                #pragma unroll
                for (int hh = 0; hh < 2; hh++)
                    pa[is][hh] = *(const bf16x8*)(Pb + (h0 + hh) * 2560 + (is*16 + l15) * 80 + l4 * 16);
            #pragma unroll
            for (int is = 0; is < 2; is++)
                #pragma unroll
                for (int hh = 0; hh < 2; hh++)
                    #pragma unroll
                    for (int n = 0; n < 4; n++)
                        acc[is][hh][n] = __builtin_amdgcn_mfma_f32_16x16x32_bf16(pa[is][hh], vf[hh][n], acc[is][hh][n], 0, 0, 0);
        }
        if (g < 15) LOAD_VF(j0 + 32);    // vf consumed -> refill for g+1
    }

    // ---- epilogue: bf16 partial
    #pragma unroll
    for (int is = 0; is < 2; is++)
        #pragma unroll
        for (int hh = 0; hh < 2; hh++)
            #pragma unroll
            for (int n = 0; n < 4; n++)
                #pragma unroll
                for (int r = 0; r < 4; r++) {
                    const long row = b * 1024 + i0 + is * 16 + l4 * 4 + r;
                    Pout[row * 1024 + (h0 + hh) * 64 + n * 16 + l15] = f2b(acc[is][hh][n][r]);
                }
#undef LOAD_KF
#undef LOAD_VF
}

// ---------------- reduce: P0 += P1 (bf16, in place) ---------------------------
__global__ __launch_bounds__(256) void addp(
    unsigned short* __restrict__ P0, const unsigned short* __restrict__ P1)
{
    const long i = ((long)blockIdx.x * 256 + threadIdx.x) * 8;
    ushort4 a0 = *(const ushort4*)(P0 + i);
    ushort4 a1 = *(const ushort4*)(P0 + i + 4);
    ushort4 b0 = *(const ushort4*)(P1 + i);
    ushort4 b1 = *(const ushort4*)(P1 + i + 4);
    ushort4 o0, o1;
    o0.x = f2b(b2f(a0.x) + b2f(b0.x)); o0.y = f2b(b2f(a0.y) + b2f(b0.y));
    o0.z = f2b(b2f(a0.z) + b2f(b0.z)); o0.w = f2b(b2f(a0.w) + b2f(b0.w));
    o1.x = f2b(b2f(a1.x) + b2f(b1.x)); o1.y = f2b(b2f(a1.y) + b2f(b1.y));
    o1.z = f2b(b2f(a1.z) + b2f(b1.z)); o1.w = f2b(b2f(a1.w) + b2f(b1.w));
    *(ushort4*)(P0 + i) = o0;
    *(ushort4*)(P0 + i + 4) = o1;
}

extern "C" void kernel_launch(void* const* d_in, const int* in_sizes, int n_in,
                              void* d_out, int out_size, void* d_ws, size_t ws_size,
                              hipStream_t stream)
{
    const float* q    = (const float*)d_in[0];
    const float* k    = (const float*)d_in[1];
    const float* v    = (const float*)d_in[2];
    const int*   mask = (const int*)  d_in[3];
    const float* Wq   = (const float*)d_in[4];
    const float* bq   = (const float*)d_in[5];
    const float* Wk   = (const float*)d_in[6];
    const float* bk   = (const float*)d_in[7];
    const float* Wv   = (const float*)d_in[8];
    const float* bv   = (const float*)d_in[9];
    const float* Wo   = (const float*)d_in[10];
    const float* bo   = (const float*)d_in[11];

    unsigned short* ws = (unsigned short*)d_ws;
    const long MS = 1048576;
    unsigned short* WT  = ws;             // 4 transposed weights      [0,4M)
    unsigned short* Xq  = ws + 4*MS;      // bf16 query  -> later Vt   [4M,8M)
    unsigned short* Xk  = ws + 8*MS;      // bf16 key    -> later P0   [8M,12M)
    unsigned short* Xv  = ws + 12*MS;     // bf16 value                [12M,16M)
    unsigned short* Qm  = ws + 16*MS;     // Q projection              [16M,20M)
    unsigned short* Km  = ws + 20*MS;     // K projection              [20M,24M)
    unsigned short* Vm  = ws + 24*MS;     // V projection -> later P1  [24M,28M)
    unsigned short* Vtm = Xq;
    unsigned short* P0  = Xk;
    unsigned short* P1  = Vm;

    convert_qkv<<<12288, 256, 0, stream>>>(q, k, v, Xq);
    wtrans<<<dim3(32, 32, 4), dim3(32, 8), 0, stream>>>(Wq, Wk, Wv, Wo, WT);
    gemm3<<<dim3(32, 8, 3), 256, 0, stream>>>(Xq, WT, bq, bk, bv, Qm);
    vtrans<<<dim3(32, 32, 4), dim3(32, 8), 0, stream>>>(Vm, Vtm);
    attn_fused<<<256, 512, 0, stream>>>(Qm, Km, Vtm, mask, P0, P1);
    addp<<<2048, 256, 0, stream>>>(P0, P1);
    gemm_bias_f32<<<dim3(32, 8), 256, 0, stream>>>(P0, WT + 3*MS, bo, (float*)d_out, 1024, 1024);
}